// Round 1
// baseline (803.241 us; speedup 1.0000x reference)
//
#include <hip/hip_runtime.h>

typedef float  f32x4   __attribute__((ext_vector_type(4)));
typedef short  short8  __attribute__((ext_vector_type(8)));
typedef short  short4v __attribute__((ext_vector_type(4)));
typedef __bf16 bf16x8  __attribute__((ext_vector_type(8)));

__device__ __forceinline__ unsigned short f2bf(float f) {
    unsigned u = __builtin_bit_cast(unsigned, f);
    unsigned r = u + 0x7fffu + ((u >> 16) & 1u);   // round-to-nearest-even
    return (unsigned short)(r >> 16);
}

// ---------------------------------------------------------------------------
// Small GEMM:  St[n][m] = sum_k X[m][k] * W[k][n]   (K = 128 fixed)
// X fp32 [M][128], W fp32 [128][NMAT], St bf16 [NMAT][M]  (transposed output)
// BM = 64 rows/block, 256 threads: thread = (m = tid%64, group = tid/64),
// each thread computes NMAT/4 output columns for its row.
// ---------------------------------------------------------------------------
template<int NMAT>
__global__ __launch_bounds__(256) void k_xw_t(const float* __restrict__ X,
                                              const float* __restrict__ W,
                                              short* __restrict__ St, int M) {
    constexpr int K   = 128;
    constexpr int NPT = NMAT / 4;            // outputs per thread (32 or 16)
    __shared__ float Xs[64][129];            // +1 pad: conflict-free scalar reads
    __shared__ float Ws[K][NMAT];

    const int tid = threadIdx.x;
    const int m0  = blockIdx.x * 64;

    // stage W (float4, coalesced)
    constexpr int WCH = K * NMAT / 4 / 256;
    #pragma unroll
    for (int j = 0; j < WCH; ++j) {
        int ch = tid + j * 256;
        ((float4*)Ws)[ch] = ((const float4*)W)[ch];
    }
    // stage X tile (float4 loads, scalar LDS writes due to odd pad)
    #pragma unroll
    for (int j = 0; j < 8; ++j) {
        int ch = tid + j * 256;             // 64 rows * 32 float4-chunks
        int r = ch >> 5, c4 = ch & 31;
        float4 v = *(const float4*)(X + (size_t)(m0 + r) * K + c4 * 4);
        Xs[r][c4 * 4 + 0] = v.x; Xs[r][c4 * 4 + 1] = v.y;
        Xs[r][c4 * 4 + 2] = v.z; Xs[r][c4 * 4 + 3] = v.w;
    }
    __syncthreads();

    const int m  = tid & 63;
    const int n0 = (tid >> 6) * NPT;
    float acc[NPT];
    #pragma unroll
    for (int i = 0; i < NPT; ++i) acc[i] = 0.f;

    for (int k = 0; k < K; ++k) {
        float x = Xs[m][k];
        #pragma unroll
        for (int i = 0; i < NPT; i += 4) {
            float4 w = *(const float4*)&Ws[k][n0 + i];   // broadcast across wave
            acc[i + 0] += x * w.x; acc[i + 1] += x * w.y;
            acc[i + 2] += x * w.z; acc[i + 3] += x * w.w;
        }
    }
    // transposed store: consecutive lanes -> consecutive m (coalesced 128B)
    #pragma unroll
    for (int i = 0; i < NPT; ++i)
        St[(size_t)(n0 + i) * M + m0 + m] = (short)f2bf(acc[i]);
}

// ---------------------------------------------------------------------------
// Streaming GEMM:  out[m][n] = sum_k adj[m][k] * S[k][n]  (+bias, opt. relu)
// adj fp32 [M][K] streamed from HBM, converted to bf16 in regs.
// Bt bf16 [BN][K] = S transposed (L2-resident, 4 MiB).
// BM=64, BK=64, 256 thr / 4 waves (2x2), wave tile 32 x (BN/2).
// LDS rows padded to 72 bf16 (144 B) -> only 2-way bank aliasing (free).
// Prefetch next K-tile into regs before MFMA phase (loads in flight across it).
// ---------------------------------------------------------------------------
template<int BN, bool RELU>
__global__ __launch_bounds__(256) void k_adj_gemm(const float* __restrict__ A,
                                                  const short* __restrict__ Bt,
                                                  const float* __restrict__ bias,
                                                  float* __restrict__ out,
                                                  int M, int K) {
    constexpr int BM  = 64, BK = 64;
    constexpr int NF  = BN / 32;             // n-frags per wave (4 or 2)
    constexpr int ACH = BM * BK / 4 / 256;   // 4 float4 chunks / thread
    constexpr int BCH = BN * BK / 8 / 256;   // 16B bf16 chunks / thread (4 or 2)

    __shared__ short As[BM][72];
    __shared__ short Bs[BN][72];

    const int tid  = threadIdx.x;
    const int row0 = blockIdx.x * BM;
    const int lane = tid & 63, wave = tid >> 6;
    const int wr = wave >> 1, wc = wave & 1;
    const int lr = lane & 15, lk = lane >> 4;

    f32x4 acc[2][NF];
    #pragma unroll
    for (int m = 0; m < 2; ++m)
        #pragma unroll
        for (int n = 0; n < NF; ++n) acc[m][n] = (f32x4)0.f;

    float4 aP[ACH];
    uint4  bP[BCH];

    const int NT = K / BK;
    // prefetch tile 0
    #pragma unroll
    for (int j = 0; j < ACH; ++j) {
        int ch = tid + j * 256, r = ch >> 4, c4 = ch & 15;
        aP[j] = *(const float4*)(A + (size_t)(row0 + r) * K + c4 * 4);
    }
    #pragma unroll
    for (int j = 0; j < BCH; ++j) {
        int ch = tid + j * 256, n = ch >> 3, c = ch & 7;
        bP[j] = *(const uint4*)(Bt + (size_t)n * K + c * 8);
    }

    for (int kt = 0; kt < NT; ++kt) {
        __syncthreads();                      // LDS free (prev compute done)
        #pragma unroll
        for (int j = 0; j < ACH; ++j) {       // fp32 -> bf16, write LDS
            int ch = tid + j * 256, r = ch >> 4, c4 = ch & 15;
            short4v s;
            s.x = (short)f2bf(aP[j].x); s.y = (short)f2bf(aP[j].y);
            s.z = (short)f2bf(aP[j].z); s.w = (short)f2bf(aP[j].w);
            *(short4v*)&As[r][c4 * 4] = s;
        }
        #pragma unroll
        for (int j = 0; j < BCH; ++j) {
            int ch = tid + j * 256, n = ch >> 3, c = ch & 7;
            *(uint4*)&Bs[n][c * 8] = bP[j];
        }
        if (kt + 1 < NT) {                    // issue next-tile loads now;
            int k0 = (kt + 1) * BK;           // waitcnt lands at next iter's write
            #pragma unroll
            for (int j = 0; j < ACH; ++j) {
                int ch = tid + j * 256, r = ch >> 4, c4 = ch & 15;
                aP[j] = *(const float4*)(A + (size_t)(row0 + r) * K + k0 + c4 * 4);
            }
            #pragma unroll
            for (int j = 0; j < BCH; ++j) {
                int ch = tid + j * 256, n = ch >> 3, c = ch & 7;
                bP[j] = *(const uint4*)(Bt + (size_t)n * K + k0 + c * 8);
            }
        }
        __syncthreads();                      // LDS ready
        #pragma unroll
        for (int s = 0; s < 2; ++s) {
            short8 a[2], b[NF];
            #pragma unroll
            for (int m = 0; m < 2; ++m)
                a[m] = *(const short8*)((const char*)&As[0][0] +
                        (wr * 32 + m * 16 + lr) * 144 + s * 64 + lk * 16);
            #pragma unroll
            for (int n = 0; n < NF; ++n)
                b[n] = *(const short8*)((const char*)&Bs[0][0] +
                        (wc * (BN / 2) + n * 16 + lr) * 144 + s * 64 + lk * 16);
            #pragma unroll
            for (int m = 0; m < 2; ++m)
                #pragma unroll
                for (int n = 0; n < NF; ++n)
                    acc[m][n] = __builtin_amdgcn_mfma_f32_16x16x32_bf16(
                        __builtin_bit_cast(bf16x8, a[m]),
                        __builtin_bit_cast(bf16x8, b[n]), acc[m][n], 0, 0, 0);
        }
    }

    // epilogue: C/D layout col = lane&15, row = (lane>>4)*4 + j  [m89-verified]
    #pragma unroll
    for (int m = 0; m < 2; ++m)
        #pragma unroll
        for (int n = 0; n < NF; ++n) {
            int col = wc * (BN / 2) + n * 16 + lr;
            float bv = bias[col];
            #pragma unroll
            for (int j = 0; j < 4; ++j) {
                int row = row0 + wr * 32 + m * 16 + lk * 4 + j;
                float v = acc[m][n][j] + bv;
                if (RELU) v = fmaxf(v, 0.f);
                out[(size_t)row * BN + col] = v;
            }
        }
}

extern "C" void kernel_launch(void* const* d_in, const int* in_sizes, int n_in,
                              void* d_out, int out_size, void* d_ws, size_t ws_size,
                              hipStream_t stream) {
    const int N = 16384, NF_ = 128, NH1 = 128, NH2 = 64;
    const float* feature = (const float*)d_in[0];
    const float* adj     = (const float*)d_in[1];
    const float* W1      = (const float*)d_in[2];
    const float* b1      = (const float*)d_in[3];
    const float* W2      = (const float*)d_in[4];
    const float* b2      = (const float*)d_in[5];

    // workspace layout (needs 14 MiB)
    short* S1t = (short*)d_ws;                            // [128][16384] bf16, 4 MiB
    float* h   = (float*)((char*)d_ws + (4u << 20));      // [16384][128] fp32, 8 MiB
    short* S2t = (short*)((char*)d_ws + (12u << 20));     // [64][16384]  bf16, 2 MiB

    // S1^T = (X @ W1)^T  (bf16)
    k_xw_t<NH1><<<N / 64, 256, 0, stream>>>(feature, W1, S1t, N);
    // h = relu(adj @ S1 + b1)  (fp32)
    k_adj_gemm<NH1, true><<<N / 64, 256, 0, stream>>>(adj, S1t, b1, h, N, N);
    // S2^T = (h @ W2)^T  (bf16)
    k_xw_t<NH2><<<N / 64, 256, 0, stream>>>(h, W2, S2t, N);
    // out = adj @ S2 + b2  (fp32)
    k_adj_gemm<NH2, false><<<N / 64, 256, 0, stream>>>(adj, S2t, b2, (float*)d_out, N, N);
    (void)in_sizes; (void)n_in; (void)out_size; (void)ws_size; (void)NF_;
}